// Round 1
// baseline (468.998 us; speedup 1.0000x reference)
//
#include <hip/hip_runtime.h>
#include <cstdint>
#include <cstddef>

// ---------------------------------------------------------------------------
// Hgru2 (GLA-style gated linear attention), B=4, N=2048, d=1024, h=8, hd=128
// Pipeline:
//   cast x,W -> bf16
//   gemm_qkv: Q=silu(xWq^T), f=sigmoid(xWk^T) -> K=1-f (bf16), G=logsigmoid(f) (f32), V (bf16)
//   phaseA  : per (b,h,chunk of 32): U^T[v][i] = sum_s V[s][v]*k[s][i]*exp(bC-b_s), D=exp(bC)
//   phaseC  : per (b,h,chunk): O = tril(Q~ K~^T) V + Q~ S,  S ~= U_{c-1} + D_{c-1} U_{c-2}
//   rmsnorm -> bf16
//   gemm_out: out = normed @ Wo^T (f32)
// ---------------------------------------------------------------------------

typedef unsigned short u16;
using f32x4  = __attribute__((ext_vector_type(4))) float;
using bf16x8 = __attribute__((ext_vector_type(8))) short;

__device__ __forceinline__ float bf2f(u16 u) {
  union { unsigned int i; float f; } v; v.i = ((unsigned int)u) << 16; return v.f;
}
__device__ __forceinline__ u16 f2bf(float f) {
  union { float f; unsigned int i; } v; v.f = f;
  unsigned int r = v.i + 0x7fffu + ((v.i >> 16) & 1u);
  return (u16)(r >> 16);
}
// async global->LDS, 16B per lane; lds dest must be wave-uniform base (+lane*16 by HW)
__device__ __forceinline__ void async_load16(const void* g, void* l) {
  __builtin_amdgcn_global_load_lds(
      (const __attribute__((address_space(1))) unsigned int*)(uintptr_t)g,
      (__attribute__((address_space(3))) unsigned int*)(uintptr_t)l, 16, 0, 0);
}

// ---------------------------------------------------------------------------
// 128x128-tile bf16 GEMM core, C = A * B^T, A[M,1024] row-major, B[N,1024] row-major
// 256 threads = 4 waves; wave quadrant 64x64; 16x(16x16x32) MFMA; BK=64
// ---------------------------------------------------------------------------
__device__ __forceinline__ void gemm128_core(const u16* __restrict__ Ag, const u16* __restrict__ Bg,
                                             u16* sA, u16* sB, f32x4 (&acc)[4][4]) {
  const int tid = threadIdx.x;
  const int lane = tid & 63, wave = tid >> 6;
  const int wm = (wave & 1) * 64, wn = (wave >> 1) * 64;
  const int r = lane & 15, quad = lane >> 4;
  for (int kt = 0; kt < 1024; kt += 64) {
    __syncthreads();
#pragma unroll
    for (int it = 0; it < 4; ++it) {
      int cidx = it * 256 + tid;
      int row = cidx >> 3, col8 = cidx & 7;
      async_load16(Ag + (size_t)row * 1024 + kt + col8 * 8, sA + (it * 256 + wave * 64) * 8);
      async_load16(Bg + (size_t)row * 1024 + kt + col8 * 8, sB + (it * 256 + wave * 64) * 8);
    }
    __syncthreads();
#pragma unroll
    for (int kk = 0; kk < 64; kk += 32) {
      bf16x8 af[4], bv[4];
#pragma unroll
      for (int i = 0; i < 4; ++i) af[i] = *(const bf16x8*)(sA + (wm + i * 16 + r) * 64 + kk + quad * 8);
#pragma unroll
      for (int j = 0; j < 4; ++j) bv[j] = *(const bf16x8*)(sB + (wn + j * 16 + r) * 64 + kk + quad * 8);
#pragma unroll
      for (int i = 0; i < 4; ++i)
#pragma unroll
        for (int j = 0; j < 4; ++j)
          acc[i][j] = __builtin_amdgcn_mfma_f32_16x16x32_bf16(af[i], bv[j], acc[i][j], 0, 0, 0);
    }
  }
}

// ---------------------------------------------------------------------------
__global__ __launch_bounds__(256) void cast_f32_bf16(const float* __restrict__ src,
                                                     u16* __restrict__ dst, int n4) {
  int i = blockIdx.x * 256 + threadIdx.x;
  if (i >= n4) return;
  float4 v = ((const float4*)src)[i];
  unsigned int lo = (unsigned)f2bf(v.x) | ((unsigned)f2bf(v.y) << 16);
  unsigned int hi = (unsigned)f2bf(v.z) | ((unsigned)f2bf(v.w) << 16);
  ((uint2*)dst)[i] = make_uint2(lo, hi);
}

// grid (64, 24): y/8 selects {Q,K,V}, y&7 = 128-col block
__global__ __launch_bounds__(256) void hgru_gemm_qkv(
    const u16* __restrict__ Xb, const u16* __restrict__ Wqb, const u16* __restrict__ Wkb,
    const u16* __restrict__ Wvb, u16* __restrict__ Qb, u16* __restrict__ Kb,
    float* __restrict__ G, u16* __restrict__ Vb) {
  __shared__ alignas(16) u16 sA[128 * 64];
  __shared__ alignas(16) u16 sB[128 * 64];
  const int which = blockIdx.y >> 3, bn = blockIdx.y & 7;
  const u16* W = which == 0 ? Wqb : (which == 1 ? Wkb : Wvb);
  const u16* Ag = Xb + (size_t)blockIdx.x * 128 * 1024;
  const u16* Bg = W + (size_t)bn * 128 * 1024;
  f32x4 acc[4][4] = {};
  gemm128_core(Ag, Bg, sA, sB, acc);
  const int tid = threadIdx.x, lane = tid & 63, wave = tid >> 6;
  const int wm = (wave & 1) * 64, wn = (wave >> 1) * 64;
  const int r = lane & 15, quad = lane >> 4;
#pragma unroll
  for (int i = 0; i < 4; ++i)
#pragma unroll
    for (int j = 0; j < 4; ++j)
#pragma unroll
      for (int reg = 0; reg < 4; ++reg) {
        int m = blockIdx.x * 128 + wm + i * 16 + quad * 4 + reg;
        int n = bn * 128 + wn + j * 16 + r;
        size_t off = (size_t)m * 1024 + n;
        float z = acc[i][j][reg];
        if (which == 0) {
          Qb[off] = f2bf(z / (1.f + __expf(-z)));      // silu
        } else if (which == 1) {
          float ek = __expf(-z);
          float fs = 1.f / (1.f + ek);                  // f = sigmoid(z)
          Kb[off] = f2bf(ek * fs);                      // k = 1 - f (exact form)
          G[off] = -log1pf(__expf(-fs));                // log_sigmoid(f)
        } else {
          Vb[off] = f2bf(z);
        }
      }
}

// phaseA: grid 2048 = (b*8+h)*64 + c.  U^T[v][i] (bf16) and D[i]=exp(b31[i]) (f32)
__global__ __launch_bounds__(256) void hgru_phaseA(
    const u16* __restrict__ Kb, const u16* __restrict__ Vb, const float* __restrict__ G,
    u16* __restrict__ SU, float* __restrict__ Dd) {
  __shared__ alignas(16) float sb[32 * 128];   // in-chunk cumsum of g
  __shared__ alignas(16) u16 sKt[128 * 40];    // khat^T [i][s]
  __shared__ alignas(16) u16 sVt[128 * 40];    // V^T    [v][s]
  const int tid = threadIdx.x, blk = blockIdx.x;
  const int c = blk & 63, bh = blk >> 6, h = bh & 7, b = bh >> 3;
  const size_t rowbase = (size_t)(b * 2048 + c * 32) * 1024 + h * 128;

  if (tid < 128) {
    float run = 0.f;
    for (int t = 0; t < 32; ++t) {
      run += G[rowbase + (size_t)t * 1024 + tid];
      sb[t * 128 + tid] = run;
    }
    Dd[(size_t)blk * 128 + tid] = __expf(run);
  }
  __syncthreads();
#pragma unroll
  for (int kq = 0; kq < 16; ++kq) {
    int idx = kq * 256 + tid;           // [s][i]
    int s = idx >> 7, i = idx & 127;
    float bC = sb[31 * 128 + i];
    float bs = sb[s * 128 + i];
    float kv = bf2f(Kb[rowbase + (size_t)s * 1024 + i]);
    sKt[i * 40 + s] = f2bf(kv * __expf(bC - bs));
    sVt[i * 40 + s] = Vb[rowbase + (size_t)s * 1024 + i];
  }
  __syncthreads();
  const int lane = tid & 63, wave = tid >> 6;
  const int wm = (wave & 1) * 64, wn = (wave >> 1) * 64;
  const int r = lane & 15, quad = lane >> 4;
  f32x4 acc[4][4] = {};
  bf16x8 af[4], bv[4];
#pragma unroll
  for (int i = 0; i < 4; ++i) af[i] = *(const bf16x8*)(sVt + (wm + i * 16 + r) * 40 + quad * 8);
#pragma unroll
  for (int j = 0; j < 4; ++j) bv[j] = *(const bf16x8*)(sKt + (wn + j * 16 + r) * 40 + quad * 8);
#pragma unroll
  for (int i = 0; i < 4; ++i)
#pragma unroll
    for (int j = 0; j < 4; ++j)
      acc[i][j] = __builtin_amdgcn_mfma_f32_16x16x32_bf16(af[i], bv[j], acc[i][j], 0, 0, 0);
  u16* SUo = SU + (size_t)blk * 16384;
#pragma unroll
  for (int i = 0; i < 4; ++i)
#pragma unroll
    for (int j = 0; j < 4; ++j)
#pragma unroll
      for (int reg = 0; reg < 4; ++reg) {
        int v = wm + i * 16 + quad * 4 + reg;
        int ii = wn + j * 16 + r;
        SUo[v * 128 + ii] = f2bf(acc[i][j][reg]);
      }
}

// phaseC smem layout (bytes): sQ[0,8704) sVt[8704,18944) sAm[18944,21504)
// union at 21504: { sb f32 16384 + sK 8704 } | { sSt u16 128x136 = 34816 } ; total 56320
__global__ __launch_bounds__(256) void hgru_phaseC(
    const u16* __restrict__ Qb, const u16* __restrict__ Kb, const u16* __restrict__ Vb,
    const float* __restrict__ G, const u16* __restrict__ SU, const float* __restrict__ Dd,
    u16* __restrict__ O) {
  __shared__ alignas(16) char smem[56320];
  u16* sQ = (u16*)(smem);                 // Q~ [t][136]
  u16* sVt = (u16*)(smem + 8704);         // V^T [v][40]
  u16* sAm = (u16*)(smem + 18944);        // masked A [t][40]
  float* sb = (float*)(smem + 21504);     // cumsum [t][128]
  u16* sK = (u16*)(smem + 37888);         // K~ [t][136]
  u16* sSt = (u16*)(smem + 21504);        // S^(c) as [v][136] (overwrites sb+sK)
  const int tid = threadIdx.x, blk = blockIdx.x;
  const int c = blk & 63, bh = blk >> 6, h = bh & 7, b = bh >> 3;
  const size_t rowbase = (size_t)(b * 2048 + c * 32) * 1024 + h * 128;

  if (tid < 128) {
    float run = 0.f;
    for (int t = 0; t < 32; ++t) {
      run += G[rowbase + (size_t)t * 1024 + tid];
      sb[t * 128 + tid] = run;
    }
  }
  __syncthreads();
#pragma unroll
  for (int kq = 0; kq < 16; ++kq) {
    int idx = kq * 256 + tid;           // [t][j]
    int t = idx >> 7, j = idx & 127;
    float bb = sb[t * 128 + j];
    float qv = bf2f(Qb[rowbase + (size_t)t * 1024 + j]);
    float kv = bf2f(Kb[rowbase + (size_t)t * 1024 + j]);
    sQ[t * 136 + j] = f2bf(qv * __expf(bb));
    sK[t * 136 + j] = f2bf(kv * __expf(-bb));
  }
#pragma unroll
  for (int kq = 0; kq < 16; ++kq) {
    int idx = kq * 256 + tid;           // [s][v] read -> [v][s] write
    int s = idx >> 7, v = idx & 127;
    sVt[v * 40 + s] = Vb[rowbase + (size_t)s * 1024 + v];
  }
  __syncthreads();
  const int lane = tid & 63, wave = tid >> 6;
  const int r = lane & 15, quad = lane >> 4;
  // GEMM1: A = Q~ K~^T (32x32, K=128), wave w -> subtile (mi=w&1, nj=w>>1)
  {
    const int mi = wave & 1, nj = wave >> 1;
    f32x4 a1 = {0.f, 0.f, 0.f, 0.f};
#pragma unroll
    for (int ks = 0; ks < 4; ++ks) {
      bf16x8 af = *(const bf16x8*)(sQ + (mi * 16 + r) * 136 + ks * 32 + quad * 8);
      bf16x8 bk = *(const bf16x8*)(sK + (nj * 16 + r) * 136 + ks * 32 + quad * 8);
      a1 = __builtin_amdgcn_mfma_f32_16x16x32_bf16(af, bk, a1, 0, 0, 0);
    }
    __syncthreads();  // all reads of sK/sb done before overwrite; sAm writes before next barrier
#pragma unroll
    for (int reg = 0; reg < 4; ++reg) {
      int t = mi * 16 + quad * 4 + reg;
      int s = nj * 16 + r;
      sAm[t * 40 + s] = (s <= t) ? f2bf(a1[reg]) : (u16)0;
    }
  }
  // stage S^(c) ~= U_{c-1} + D_{c-1} * U_{c-2}   into sSt[v][136]
  {
    const int c1 = (c >= 1) ? c - 1 : 0;
    const int c2 = (c >= 2) ? c - 2 : 0;
    const u16* U1 = SU + (size_t)(bh * 64 + c1) * 16384;
    const u16* U2 = SU + (size_t)(bh * 64 + c2) * 16384;
    const float* D1 = Dd + (size_t)(bh * 64 + c1) * 128;
#pragma unroll
    for (int g8 = 0; g8 < 8; ++g8) {
      int idx = g8 * 256 + tid;          // 2048 groups of 8 elements
      int v = idx >> 4, ic = idx & 15;
      float vals[8];
#pragma unroll
      for (int e = 0; e < 8; ++e) vals[e] = 0.f;
      if (c >= 1) {
        uint4 raw = *(const uint4*)(U1 + v * 128 + ic * 8);
        vals[0] = bf2f((u16)(raw.x & 0xffff)); vals[1] = bf2f((u16)(raw.x >> 16));
        vals[2] = bf2f((u16)(raw.y & 0xffff)); vals[3] = bf2f((u16)(raw.y >> 16));
        vals[4] = bf2f((u16)(raw.z & 0xffff)); vals[5] = bf2f((u16)(raw.z >> 16));
        vals[6] = bf2f((u16)(raw.w & 0xffff)); vals[7] = bf2f((u16)(raw.w >> 16));
      }
      if (c >= 2) {
        uint4 raw = *(const uint4*)(U2 + v * 128 + ic * 8);
        float4 da = ((const float4*)D1)[ic * 2];
        float4 db = ((const float4*)D1)[ic * 2 + 1];
        vals[0] += da.x * bf2f((u16)(raw.x & 0xffff)); vals[1] += da.y * bf2f((u16)(raw.x >> 16));
        vals[2] += da.z * bf2f((u16)(raw.y & 0xffff)); vals[3] += da.w * bf2f((u16)(raw.y >> 16));
        vals[4] += db.x * bf2f((u16)(raw.z & 0xffff)); vals[5] += db.y * bf2f((u16)(raw.z >> 16));
        vals[6] += db.z * bf2f((u16)(raw.w & 0xffff)); vals[7] += db.w * bf2f((u16)(raw.w >> 16));
      }
      uint4 o;
      o.x = (unsigned)f2bf(vals[0]) | ((unsigned)f2bf(vals[1]) << 16);
      o.y = (unsigned)f2bf(vals[2]) | ((unsigned)f2bf(vals[3]) << 16);
      o.z = (unsigned)f2bf(vals[4]) | ((unsigned)f2bf(vals[5]) << 16);
      o.w = (unsigned)f2bf(vals[6]) | ((unsigned)f2bf(vals[7]) << 16);
      *(uint4*)(sSt + v * 136 + ic * 8) = o;
    }
  }
  __syncthreads();
  // GEMM2: O[t][v] = sum_s Am[t][s] V[s][v] + sum_i Q~[t][i] S[i][v]
  f32x4 acc2[2][2] = {};
#pragma unroll
  for (int mi = 0; mi < 2; ++mi) {
    bf16x8 af = *(const bf16x8*)(sAm + (mi * 16 + r) * 40 + quad * 8);
#pragma unroll
    for (int nj = 0; nj < 2; ++nj) {
      bf16x8 bv = *(const bf16x8*)(sVt + (wave * 32 + nj * 16 + r) * 40 + quad * 8);
      acc2[mi][nj] = __builtin_amdgcn_mfma_f32_16x16x32_bf16(af, bv, acc2[mi][nj], 0, 0, 0);
    }
  }
#pragma unroll
  for (int ks = 0; ks < 4; ++ks) {
    bf16x8 afq[2], bst[2];
#pragma unroll
    for (int mi = 0; mi < 2; ++mi)
      afq[mi] = *(const bf16x8*)(sQ + (mi * 16 + r) * 136 + ks * 32 + quad * 8);
#pragma unroll
    for (int nj = 0; nj < 2; ++nj)
      bst[nj] = *(const bf16x8*)(sSt + (wave * 32 + nj * 16 + r) * 136 + ks * 32 + quad * 8);
#pragma unroll
    for (int mi = 0; mi < 2; ++mi)
#pragma unroll
      for (int nj = 0; nj < 2; ++nj)
        acc2[mi][nj] = __builtin_amdgcn_mfma_f32_16x16x32_bf16(afq[mi], bst[nj], acc2[mi][nj], 0, 0, 0);
  }
#pragma unroll
  for (int mi = 0; mi < 2; ++mi)
#pragma unroll
    for (int nj = 0; nj < 2; ++nj)
#pragma unroll
      for (int reg = 0; reg < 4; ++reg) {
        int t = mi * 16 + quad * 4 + reg;
        int v = wave * 32 + nj * 16 + r;
        O[rowbase + (size_t)t * 1024 + v] = f2bf(acc2[mi][nj][reg]);
      }
}

__global__ __launch_bounds__(256) void hgru_rmsnorm(const u16* __restrict__ O,
                                                    const float* __restrict__ w,
                                                    u16* __restrict__ On) {
  __shared__ float sred[4];
  const int row = blockIdx.x, tid = threadIdx.x;
  const size_t base = (size_t)row * 1024;
  float vals[4];
  float ss = 0.f;
#pragma unroll
  for (int k = 0; k < 4; ++k) {
    float v = bf2f(O[base + k * 256 + tid]);
    vals[k] = v;
    ss += v * v;
  }
#pragma unroll
  for (int m = 32; m >= 1; m >>= 1) ss += __shfl_xor(ss, m);
  if ((tid & 63) == 0) sred[tid >> 6] = ss;
  __syncthreads();
  float tot = sred[0] + sred[1] + sred[2] + sred[3];
  float scale = rsqrtf(tot * (1.f / 1024.f) + 1e-6f);
#pragma unroll
  for (int k = 0; k < 4; ++k)
    On[base + k * 256 + tid] = f2bf(vals[k] * scale * w[k * 256 + tid]);
}

__global__ __launch_bounds__(256) void hgru_gemm_out(const u16* __restrict__ Ab,
                                                     const u16* __restrict__ Wob,
                                                     float* __restrict__ out) {
  __shared__ alignas(16) u16 sA[128 * 64];
  __shared__ alignas(16) u16 sB[128 * 64];
  const u16* Ag = Ab + (size_t)blockIdx.x * 128 * 1024;
  const u16* Bg = Wob + (size_t)blockIdx.y * 128 * 1024;
  f32x4 acc[4][4] = {};
  gemm128_core(Ag, Bg, sA, sB, acc);
  const int tid = threadIdx.x, lane = tid & 63, wave = tid >> 6;
  const int wm = (wave & 1) * 64, wn = (wave >> 1) * 64;
  const int r = lane & 15, quad = lane >> 4;
#pragma unroll
  for (int i = 0; i < 4; ++i)
#pragma unroll
    for (int j = 0; j < 4; ++j)
#pragma unroll
      for (int reg = 0; reg < 4; ++reg) {
        int m = blockIdx.x * 128 + wm + i * 16 + quad * 4 + reg;
        int n = blockIdx.y * 128 + wn + j * 16 + r;
        out[(size_t)m * 1024 + n] = acc[i][j][reg];
      }
}

// ---------------------------------------------------------------------------
extern "C" void kernel_launch(void* const* d_in, const int* in_sizes, int n_in,
                              void* d_out, int out_size, void* d_ws, size_t ws_size,
                              hipStream_t stream) {
  const float* x  = (const float*)d_in[0];
  const float* Wq = (const float*)d_in[1];
  const float* Wk = (const float*)d_in[2];
  const float* Wv = (const float*)d_in[3];
  const float* Wo = (const float*)d_in[4];
  const float* nw = (const float*)d_in[5];
  float* out = (float*)d_out;
  char* ws = (char*)d_ws;

  // ws layout (bytes); total 193,986,560
  u16* Xb   = (u16*)(ws + 0);            // 16 MB  x bf16 (later reused as normed output)
  u16* Wqb  = (u16*)(ws + 16777216);
  u16* Wkb  = (u16*)(ws + 18874368);
  u16* Wvb  = (u16*)(ws + 20971520);
  u16* Wob  = (u16*)(ws + 23068672);
  u16* Qb   = (u16*)(ws + 25165824);
  u16* Kb   = (u16*)(ws + 41943040);
  u16* Vb   = (u16*)(ws + 58720256);
  float* G  = (float*)(ws + 75497472);   // 32 MB
  u16* SU   = (u16*)(ws + 109051904);    // 64 MB  [2048][128][128] U^T bf16
  float* Dd = (float*)(ws + 176160768);  // 1 MB   [2048][128]
  u16* Obf  = (u16*)(ws + 177209344);    // 16 MB  scan output bf16
  u16* On   = Xb;                        // normed output (x dead by then)

  cast_f32_bf16<<<8192, 256, 0, stream>>>(x, Xb, 2097152);
  cast_f32_bf16<<<1024, 256, 0, stream>>>(Wq, Wqb, 262144);
  cast_f32_bf16<<<1024, 256, 0, stream>>>(Wk, Wkb, 262144);
  cast_f32_bf16<<<1024, 256, 0, stream>>>(Wv, Wvb, 262144);
  cast_f32_bf16<<<1024, 256, 0, stream>>>(Wo, Wob, 262144);

  dim3 gq(64, 24);
  hgru_gemm_qkv<<<gq, 256, 0, stream>>>(Xb, Wqb, Wkb, Wvb, Qb, Kb, G, Vb);
  hgru_phaseA<<<2048, 256, 0, stream>>>(Kb, Vb, G, SU, Dd);
  hgru_phaseC<<<2048, 256, 0, stream>>>(Qb, Kb, Vb, G, SU, Dd, Obf);
  hgru_rmsnorm<<<8192, 256, 0, stream>>>(Obf, nw, On);
  dim3 go(64, 8);
  hgru_gemm_out<<<go, 256, 0, stream>>>(On, Wob, out);
}

// Round 2
// 314.087 us; speedup vs baseline: 1.4932x; 1.4932x over previous
//
#include <hip/hip_runtime.h>
#include <cstdint>
#include <cstddef>

// ---------------------------------------------------------------------------
// Hgru2 (GLA-style gated linear attention), B=4, N=2048, d=1024, h=8, hd=128
// Pipeline:
//   cast x,W -> bf16
//   gemm_qkv: Q=silu(xWq^T), f=sigmoid(xWk^T) -> K=1-f (bf16), G=logsigmoid(f) (f32), V (bf16)
//   phaseA  : per (b,h,chunk of 32): U^T[v][i] = sum_s V[s][v]*k[s][i]*exp(bC-b_s), D=exp(bC)
//   phaseC  : per (b,h,chunk): O = tril(Q~ K~^T) V + Q~ S,  S ~= U_{c-1} + D_{c-1} U_{c-2}
//   rmsnorm -> bf16
//   gemm_out: out = normed @ Wo^T (f32)
// R2: GEMM core restructured — prefetch double-buffer (issue-after-barrier,
//     1 barrier/K-step, latency hidden by compute) + XOR bank swizzle on the
//     k-group (applied to the global src addr; all 32 banks used on ds_read).
// ---------------------------------------------------------------------------

typedef unsigned short u16;
using f32x4  = __attribute__((ext_vector_type(4))) float;
using bf16x8 = __attribute__((ext_vector_type(8))) short;

__device__ __forceinline__ float bf2f(u16 u) {
  union { unsigned int i; float f; } v; v.i = ((unsigned int)u) << 16; return v.f;
}
__device__ __forceinline__ u16 f2bf(float f) {
  union { float f; unsigned int i; } v; v.f = f;
  unsigned int r = v.i + 0x7fffu + ((v.i >> 16) & 1u);
  return (u16)(r >> 16);
}
// async global->LDS, 16B per lane; lds dest must be wave-uniform base (+lane*16 by HW)
__device__ __forceinline__ void async_load16(const void* g, void* l) {
  __builtin_amdgcn_global_load_lds(
      (const __attribute__((address_space(1))) unsigned int*)(uintptr_t)g,
      (__attribute__((address_space(3))) unsigned int*)(uintptr_t)l, 16, 0, 0);
}

// ---------------------------------------------------------------------------
// 128x128-tile bf16 GEMM core, C = A * B^T, A[M,1024] row-major, B[N,1024] row-major
// 256 threads = 4 waves; wave quadrant 64x64; 16x(16x16x32) MFMA; BK=64,
// double-buffered (2x32KB), k-group XOR-swizzled by (row&7).
// ---------------------------------------------------------------------------
__device__ __forceinline__ void stage_tile(const u16* __restrict__ Ag, const u16* __restrict__ Bg,
                                           int kt, u16* sA, u16* sB, int tid, int wave) {
#pragma unroll
  for (int it = 0; it < 4; ++it) {
    int cidx = it * 256 + tid;
    int row = cidx >> 3;
    int g = (cidx & 7) ^ (row & 7);            // swizzle on global src; LDS dest stays lane-order
    async_load16(Ag + (size_t)row * 1024 + kt + g * 8, sA + (it * 256 + wave * 64) * 8);
    async_load16(Bg + (size_t)row * 1024 + kt + g * 8, sB + (it * 256 + wave * 64) * 8);
  }
}

__device__ __forceinline__ void gemm128_core(const u16* __restrict__ Ag, const u16* __restrict__ Bg,
                                             u16* sA0, u16* sB0, u16* sA1, u16* sB1,
                                             f32x4 (&acc)[4][4]) {
  const int tid = threadIdx.x;
  const int lane = tid & 63, wave = tid >> 6;
  const int wm = (wave & 1) * 64, wn = (wave >> 1) * 64;
  const int r = lane & 15, quad = lane >> 4;
  const int xk = r & 7;                        // row&7 of every fragment row this lane reads
  stage_tile(Ag, Bg, 0, sA0, sB0, tid, wave);
#pragma unroll 2
  for (int kt = 0; kt < 16; ++kt) {
    u16* cA = (kt & 1) ? sA1 : sA0;
    u16* cB = (kt & 1) ? sB1 : sB0;
    __syncthreads();                           // drains cur-buffer loads (issued 1 compute-phase ago)
    if (kt < 15) {
      u16* nA = (kt & 1) ? sA0 : sA1;
      u16* nB = (kt & 1) ? sB0 : sB1;
      stage_tile(Ag, Bg, (kt + 1) * 64, nA, nB, tid, wave);  // safe: all waves past barrier
    }
#pragma unroll
    for (int kk = 0; kk < 64; kk += 32) {
      bf16x8 af[4], bv[4];
#pragma unroll
      for (int i = 0; i < 4; ++i)
        af[i] = *(const bf16x8*)(cA + (wm + i * 16 + r) * 64 + (((kk >> 3) + quad) ^ xk) * 8);
#pragma unroll
      for (int j = 0; j < 4; ++j)
        bv[j] = *(const bf16x8*)(cB + (wn + j * 16 + r) * 64 + (((kk >> 3) + quad) ^ xk) * 8);
#pragma unroll
      for (int i = 0; i < 4; ++i)
#pragma unroll
        for (int j = 0; j < 4; ++j)
          acc[i][j] = __builtin_amdgcn_mfma_f32_16x16x32_bf16(af[i], bv[j], acc[i][j], 0, 0, 0);
    }
  }
}

// ---------------------------------------------------------------------------
__global__ __launch_bounds__(256) void cast_f32_bf16(const float* __restrict__ src,
                                                     u16* __restrict__ dst, int n4) {
  int i = blockIdx.x * 256 + threadIdx.x;
  if (i >= n4) return;
  float4 v = ((const float4*)src)[i];
  unsigned int lo = (unsigned)f2bf(v.x) | ((unsigned)f2bf(v.y) << 16);
  unsigned int hi = (unsigned)f2bf(v.z) | ((unsigned)f2bf(v.w) << 16);
  ((uint2*)dst)[i] = make_uint2(lo, hi);
}

// 4 weight matrices in one launch: grid (1024, 4)
__global__ __launch_bounds__(256) void cast_w4(const float* __restrict__ w0, const float* __restrict__ w1,
                                               const float* __restrict__ w2, const float* __restrict__ w3,
                                               u16* __restrict__ d0, u16* __restrict__ d1,
                                               u16* __restrict__ d2, u16* __restrict__ d3) {
  const float* src = blockIdx.y == 0 ? w0 : (blockIdx.y == 1 ? w1 : (blockIdx.y == 2 ? w2 : w3));
  u16* dst = blockIdx.y == 0 ? d0 : (blockIdx.y == 1 ? d1 : (blockIdx.y == 2 ? d2 : d3));
  int i = blockIdx.x * 256 + threadIdx.x;
  float4 v = ((const float4*)src)[i];
  unsigned int lo = (unsigned)f2bf(v.x) | ((unsigned)f2bf(v.y) << 16);
  unsigned int hi = (unsigned)f2bf(v.z) | ((unsigned)f2bf(v.w) << 16);
  ((uint2*)dst)[i] = make_uint2(lo, hi);
}

// grid (64, 24): y/8 selects {Q,K,V}, y&7 = 128-col block
__global__ __launch_bounds__(256) void hgru_gemm_qkv(
    const u16* __restrict__ Xb, const u16* __restrict__ Wqb, const u16* __restrict__ Wkb,
    const u16* __restrict__ Wvb, u16* __restrict__ Qb, u16* __restrict__ Kb,
    float* __restrict__ G, u16* __restrict__ Vb) {
  __shared__ alignas(16) u16 sA0[8192], sB0[8192], sA1[8192], sB1[8192];
  const int which = blockIdx.y >> 3, bn = blockIdx.y & 7;
  const u16* W = which == 0 ? Wqb : (which == 1 ? Wkb : Wvb);
  const u16* Ag = Xb + (size_t)blockIdx.x * 128 * 1024;
  const u16* Bg = W + (size_t)bn * 128 * 1024;
  f32x4 acc[4][4] = {};
  gemm128_core(Ag, Bg, sA0, sB0, sA1, sB1, acc);
  const int tid = threadIdx.x, lane = tid & 63, wave = tid >> 6;
  const int wm = (wave & 1) * 64, wn = (wave >> 1) * 64;
  const int r = lane & 15, quad = lane >> 4;
#pragma unroll
  for (int i = 0; i < 4; ++i)
#pragma unroll
    for (int j = 0; j < 4; ++j)
#pragma unroll
      for (int reg = 0; reg < 4; ++reg) {
        int m = blockIdx.x * 128 + wm + i * 16 + quad * 4 + reg;
        int n = bn * 128 + wn + j * 16 + r;
        size_t off = (size_t)m * 1024 + n;
        float z = acc[i][j][reg];
        if (which == 0) {
          Qb[off] = f2bf(z / (1.f + __expf(-z)));      // silu
        } else if (which == 1) {
          float ek = __expf(-z);
          float fs = 1.f / (1.f + ek);                  // f = sigmoid(z)
          Kb[off] = f2bf(ek * fs);                      // k = 1 - f (exact form)
          G[off] = -log1pf(__expf(-fs));                // log_sigmoid(f)
        } else {
          Vb[off] = f2bf(z);
        }
      }
}

// phaseA: grid 2048 = (b*8+h)*64 + c.  U^T[v][i] (bf16) and D[i]=exp(b31[i]) (f32)
__global__ __launch_bounds__(256) void hgru_phaseA(
    const u16* __restrict__ Kb, const u16* __restrict__ Vb, const float* __restrict__ G,
    u16* __restrict__ SU, float* __restrict__ Dd) {
  __shared__ alignas(16) float sb[32 * 128];   // in-chunk cumsum of g
  __shared__ alignas(16) u16 sKt[128 * 40];    // khat^T [i][s]
  __shared__ alignas(16) u16 sVt[128 * 40];    // V^T    [v][s]
  const int tid = threadIdx.x, blk = blockIdx.x;
  const int c = blk & 63, bh = blk >> 6, h = bh & 7, b = bh >> 3;
  const size_t rowbase = (size_t)(b * 2048 + c * 32) * 1024 + h * 128;

  if (tid < 128) {
    float run = 0.f;
    for (int t = 0; t < 32; ++t) {
      run += G[rowbase + (size_t)t * 1024 + tid];
      sb[t * 128 + tid] = run;
    }
    Dd[(size_t)blk * 128 + tid] = __expf(run);
  }
  __syncthreads();
#pragma unroll
  for (int kq = 0; kq < 16; ++kq) {
    int idx = kq * 256 + tid;           // [s][i]
    int s = idx >> 7, i = idx & 127;
    float bC = sb[31 * 128 + i];
    float bs = sb[s * 128 + i];
    float kv = bf2f(Kb[rowbase + (size_t)s * 1024 + i]);
    sKt[i * 40 + s] = f2bf(kv * __expf(bC - bs));
    sVt[i * 40 + s] = Vb[rowbase + (size_t)s * 1024 + i];
  }
  __syncthreads();
  const int lane = tid & 63, wave = tid >> 6;
  const int wm = (wave & 1) * 64, wn = (wave >> 1) * 64;
  const int r = lane & 15, quad = lane >> 4;
  f32x4 acc[4][4] = {};
  bf16x8 af[4], bv[4];
#pragma unroll
  for (int i = 0; i < 4; ++i) af[i] = *(const bf16x8*)(sVt + (wm + i * 16 + r) * 40 + quad * 8);
#pragma unroll
  for (int j = 0; j < 4; ++j) bv[j] = *(const bf16x8*)(sKt + (wn + j * 16 + r) * 40 + quad * 8);
#pragma unroll
  for (int i = 0; i < 4; ++i)
#pragma unroll
    for (int j = 0; j < 4; ++j)
      acc[i][j] = __builtin_amdgcn_mfma_f32_16x16x32_bf16(af[i], bv[j], acc[i][j], 0, 0, 0);
  u16* SUo = SU + (size_t)blk * 16384;
#pragma unroll
  for (int i = 0; i < 4; ++i)
#pragma unroll
    for (int j = 0; j < 4; ++j)
#pragma unroll
      for (int reg = 0; reg < 4; ++reg) {
        int v = wm + i * 16 + quad * 4 + reg;
        int ii = wn + j * 16 + r;
        SUo[v * 128 + ii] = f2bf(acc[i][j][reg]);
      }
}

// phaseC smem layout (bytes): sQ[0,8704) sVt[8704,18944) sAm[18944,21504)
// union at 21504: { sb f32 16384 + sK 8704 } | { sSt u16 128x136 = 34816 } ; total 56320
__global__ __launch_bounds__(256) void hgru_phaseC(
    const u16* __restrict__ Qb, const u16* __restrict__ Kb, const u16* __restrict__ Vb,
    const float* __restrict__ G, const u16* __restrict__ SU, const float* __restrict__ Dd,
    u16* __restrict__ O) {
  __shared__ alignas(16) char smem[56320];
  u16* sQ = (u16*)(smem);                 // Q~ [t][136]
  u16* sVt = (u16*)(smem + 8704);         // V^T [v][40]
  u16* sAm = (u16*)(smem + 18944);        // masked A [t][40]
  float* sb = (float*)(smem + 21504);     // cumsum [t][128]
  u16* sK = (u16*)(smem + 37888);         // K~ [t][136]
  u16* sSt = (u16*)(smem + 21504);        // S^(c) as [v][136] (overwrites sb+sK)
  const int tid = threadIdx.x, blk = blockIdx.x;
  const int c = blk & 63, bh = blk >> 6, h = bh & 7, b = bh >> 3;
  const size_t rowbase = (size_t)(b * 2048 + c * 32) * 1024 + h * 128;

  if (tid < 128) {
    float run = 0.f;
    for (int t = 0; t < 32; ++t) {
      run += G[rowbase + (size_t)t * 1024 + tid];
      sb[t * 128 + tid] = run;
    }
  }
  __syncthreads();
#pragma unroll
  for (int kq = 0; kq < 16; ++kq) {
    int idx = kq * 256 + tid;           // [t][j]
    int t = idx >> 7, j = idx & 127;
    float bb = sb[t * 128 + j];
    float qv = bf2f(Qb[rowbase + (size_t)t * 1024 + j]);
    float kv = bf2f(Kb[rowbase + (size_t)t * 1024 + j]);
    sQ[t * 136 + j] = f2bf(qv * __expf(bb));
    sK[t * 136 + j] = f2bf(kv * __expf(-bb));
  }
#pragma unroll
  for (int kq = 0; kq < 16; ++kq) {
    int idx = kq * 256 + tid;           // [s][v] read -> [v][s] write
    int s = idx >> 7, v = idx & 127;
    sVt[v * 40 + s] = Vb[rowbase + (size_t)s * 1024 + v];
  }
  __syncthreads();
  const int lane = tid & 63, wave = tid >> 6;
  const int r = lane & 15, quad = lane >> 4;
  // GEMM1: A = Q~ K~^T (32x32, K=128), wave w -> subtile (mi=w&1, nj=w>>1)
  {
    const int mi = wave & 1, nj = wave >> 1;
    f32x4 a1 = {0.f, 0.f, 0.f, 0.f};
#pragma unroll
    for (int ks = 0; ks < 4; ++ks) {
      bf16x8 af = *(const bf16x8*)(sQ + (mi * 16 + r) * 136 + ks * 32 + quad * 8);
      bf16x8 bk = *(const bf16x8*)(sK + (nj * 16 + r) * 136 + ks * 32 + quad * 8);
      a1 = __builtin_amdgcn_mfma_f32_16x16x32_bf16(af, bk, a1, 0, 0, 0);
    }
    __syncthreads();  // all reads of sK/sb done before overwrite; sAm writes before next barrier
#pragma unroll
    for (int reg = 0; reg < 4; ++reg) {
      int t = mi * 16 + quad * 4 + reg;
      int s = nj * 16 + r;
      sAm[t * 40 + s] = (s <= t) ? f2bf(a1[reg]) : (u16)0;
    }
  }
  // stage S^(c) ~= U_{c-1} + D_{c-1} * U_{c-2}   into sSt[v][136]
  {
    const int c1 = (c >= 1) ? c - 1 : 0;
    const int c2 = (c >= 2) ? c - 2 : 0;
    const u16* U1 = SU + (size_t)(bh * 64 + c1) * 16384;
    const u16* U2 = SU + (size_t)(bh * 64 + c2) * 16384;
    const float* D1 = Dd + (size_t)(bh * 64 + c1) * 128;
#pragma unroll
    for (int g8 = 0; g8 < 8; ++g8) {
      int idx = g8 * 256 + tid;          // 2048 groups of 8 elements
      int v = idx >> 4, ic = idx & 15;
      float vals[8];
#pragma unroll
      for (int e = 0; e < 8; ++e) vals[e] = 0.f;
      if (c >= 1) {
        uint4 raw = *(const uint4*)(U1 + v * 128 + ic * 8);
        vals[0] = bf2f((u16)(raw.x & 0xffff)); vals[1] = bf2f((u16)(raw.x >> 16));
        vals[2] = bf2f((u16)(raw.y & 0xffff)); vals[3] = bf2f((u16)(raw.y >> 16));
        vals[4] = bf2f((u16)(raw.z & 0xffff)); vals[5] = bf2f((u16)(raw.z >> 16));
        vals[6] = bf2f((u16)(raw.w & 0xffff)); vals[7] = bf2f((u16)(raw.w >> 16));
      }
      if (c >= 2) {
        uint4 raw = *(const uint4*)(U2 + v * 128 + ic * 8);
        float4 da = ((const float4*)D1)[ic * 2];
        float4 db = ((const float4*)D1)[ic * 2 + 1];
        vals[0] += da.x * bf2f((u16)(raw.x & 0xffff)); vals[1] += da.y * bf2f((u16)(raw.x >> 16));
        vals[2] += da.z * bf2f((u16)(raw.y & 0xffff)); vals[3] += da.w * bf2f((u16)(raw.y >> 16));
        vals[4] += db.x * bf2f((u16)(raw.z & 0xffff)); vals[5] += db.y * bf2f((u16)(raw.z >> 16));
        vals[6] += db.z * bf2f((u16)(raw.w & 0xffff)); vals[7] += db.w * bf2f((u16)(raw.w >> 16));
      }
      uint4 o;
      o.x = (unsigned)f2bf(vals[0]) | ((unsigned)f2bf(vals[1]) << 16);
      o.y = (unsigned)f2bf(vals[2]) | ((unsigned)f2bf(vals[3]) << 16);
      o.z = (unsigned)f2bf(vals[4]) | ((unsigned)f2bf(vals[5]) << 16);
      o.w = (unsigned)f2bf(vals[6]) | ((unsigned)f2bf(vals[7]) << 16);
      *(uint4*)(sSt + v * 136 + ic * 8) = o;
    }
  }
  __syncthreads();
  // GEMM2: O[t][v] = sum_s Am[t][s] V[s][v] + sum_i Q~[t][i] S[i][v]
  f32x4 acc2[2][2] = {};
#pragma unroll
  for (int mi = 0; mi < 2; ++mi) {
    bf16x8 af = *(const bf16x8*)(sAm + (mi * 16 + r) * 40 + quad * 8);
#pragma unroll
    for (int nj = 0; nj < 2; ++nj) {
      bf16x8 bv = *(const bf16x8*)(sVt + (wave * 32 + nj * 16 + r) * 40 + quad * 8);
      acc2[mi][nj] = __builtin_amdgcn_mfma_f32_16x16x32_bf16(af, bv, acc2[mi][nj], 0, 0, 0);
    }
  }
#pragma unroll
  for (int ks = 0; ks < 4; ++ks) {
    bf16x8 afq[2], bst[2];
#pragma unroll
    for (int mi = 0; mi < 2; ++mi)
      afq[mi] = *(const bf16x8*)(sQ + (mi * 16 + r) * 136 + ks * 32 + quad * 8);
#pragma unroll
    for (int nj = 0; nj < 2; ++nj)
      bst[nj] = *(const bf16x8*)(sSt + (wave * 32 + nj * 16 + r) * 136 + ks * 32 + quad * 8);
#pragma unroll
    for (int mi = 0; mi < 2; ++mi)
#pragma unroll
      for (int nj = 0; nj < 2; ++nj)
        acc2[mi][nj] = __builtin_amdgcn_mfma_f32_16x16x32_bf16(afq[mi], bst[nj], acc2[mi][nj], 0, 0, 0);
  }
#pragma unroll
  for (int mi = 0; mi < 2; ++mi)
#pragma unroll
    for (int nj = 0; nj < 2; ++nj)
#pragma unroll
      for (int reg = 0; reg < 4; ++reg) {
        int t = mi * 16 + quad * 4 + reg;
        int v = wave * 32 + nj * 16 + r;
        O[rowbase + (size_t)t * 1024 + v] = f2bf(acc2[mi][nj][reg]);
      }
}

__global__ __launch_bounds__(256) void hgru_rmsnorm(const u16* __restrict__ O,
                                                    const float* __restrict__ w,
                                                    u16* __restrict__ On) {
  __shared__ float sred[4];
  const int row = blockIdx.x, tid = threadIdx.x;
  const size_t base = (size_t)row * 1024;
  float vals[4];
  float ss = 0.f;
#pragma unroll
  for (int k = 0; k < 4; ++k) {
    float v = bf2f(O[base + k * 256 + tid]);
    vals[k] = v;
    ss += v * v;
  }
#pragma unroll
  for (int m = 32; m >= 1; m >>= 1) ss += __shfl_xor(ss, m);
  if ((tid & 63) == 0) sred[tid >> 6] = ss;
  __syncthreads();
  float tot = sred[0] + sred[1] + sred[2] + sred[3];
  float scale = rsqrtf(tot * (1.f / 1024.f) + 1e-6f);
#pragma unroll
  for (int k = 0; k < 4; ++k)
    On[base + k * 256 + tid] = f2bf(vals[k] * scale * w[k * 256 + tid]);
}

__global__ __launch_bounds__(256) void hgru_gemm_out(const u16* __restrict__ Ab,
                                                     const u16* __restrict__ Wob,
                                                     float* __restrict__ out) {
  __shared__ alignas(16) u16 sA0[8192], sB0[8192], sA1[8192], sB1[8192];
  const u16* Ag = Ab + (size_t)blockIdx.x * 128 * 1024;
  const u16* Bg = Wob + (size_t)blockIdx.y * 128 * 1024;
  f32x4 acc[4][4] = {};
  gemm128_core(Ag, Bg, sA0, sB0, sA1, sB1, acc);
  const int tid = threadIdx.x, lane = tid & 63, wave = tid >> 6;
  const int wm = (wave & 1) * 64, wn = (wave >> 1) * 64;
  const int r = lane & 15, quad = lane >> 4;
#pragma unroll
  for (int i = 0; i < 4; ++i)
#pragma unroll
    for (int j = 0; j < 4; ++j)
#pragma unroll
      for (int reg = 0; reg < 4; ++reg) {
        int m = blockIdx.x * 128 + wm + i * 16 + quad * 4 + reg;
        int n = blockIdx.y * 128 + wn + j * 16 + r;
        out[(size_t)m * 1024 + n] = acc[i][j][reg];
      }
}

// ---------------------------------------------------------------------------
extern "C" void kernel_launch(void* const* d_in, const int* in_sizes, int n_in,
                              void* d_out, int out_size, void* d_ws, size_t ws_size,
                              hipStream_t stream) {
  const float* x  = (const float*)d_in[0];
  const float* Wq = (const float*)d_in[1];
  const float* Wk = (const float*)d_in[2];
  const float* Wv = (const float*)d_in[3];
  const float* Wo = (const float*)d_in[4];
  const float* nw = (const float*)d_in[5];
  float* out = (float*)d_out;
  char* ws = (char*)d_ws;

  // ws layout (bytes); total 193,986,560
  u16* Xb   = (u16*)(ws + 0);            // 16 MB  x bf16 (later reused as normed output)
  u16* Wqb  = (u16*)(ws + 16777216);
  u16* Wkb  = (u16*)(ws + 18874368);
  u16* Wvb  = (u16*)(ws + 20971520);
  u16* Wob  = (u16*)(ws + 23068672);
  u16* Qb   = (u16*)(ws + 25165824);
  u16* Kb   = (u16*)(ws + 41943040);
  u16* Vb   = (u16*)(ws + 58720256);
  float* G  = (float*)(ws + 75497472);   // 32 MB
  u16* SU   = (u16*)(ws + 109051904);    // 64 MB  [2048][128][128] U^T bf16
  float* Dd = (float*)(ws + 176160768);  // 1 MB   [2048][128]
  u16* Obf  = (u16*)(ws + 177209344);    // 16 MB  scan output bf16
  u16* On   = Xb;                        // normed output (x dead by then)

  cast_f32_bf16<<<8192, 256, 0, stream>>>(x, Xb, 2097152);
  dim3 gw(1024, 4);
  cast_w4<<<gw, 256, 0, stream>>>(Wq, Wk, Wv, Wo, Wqb, Wkb, Wvb, Wob);

  dim3 gq(64, 24);
  hgru_gemm_qkv<<<gq, 256, 0, stream>>>(Xb, Wqb, Wkb, Wvb, Qb, Kb, G, Vb);
  hgru_phaseA<<<2048, 256, 0, stream>>>(Kb, Vb, G, SU, Dd);
  hgru_phaseC<<<2048, 256, 0, stream>>>(Qb, Kb, Vb, G, SU, Dd, Obf);
  hgru_rmsnorm<<<8192, 256, 0, stream>>>(Obf, nw, On);
  dim3 go(64, 8);
  hgru_gemm_out<<<go, 256, 0, stream>>>(On, Wob, out);
}